// Round 4
// baseline (347.234 us; speedup 1.0000x reference)
//
#include <hip/hip_runtime.h>

#define HID 8
#define OBS_LEN 8
#define PRED_LEN 12
#define SCALE 4.4f
#define BLOCK 256
#define ELEMS_PER_BLOCK 256   // 4 waves * 64 elems per wave (2 streams of 32)

#define LOG2E 1.44269504f
// exp2-arg clamp on the cn (cell) path only (|c| grows ~1/step): cap at 16.
// Gate preacts are structurally bounded -> no clamp needed there.
#define ECLAMP 16.0f

typedef __attribute__((ext_vector_type(8)))  _Float16 half8;
typedef __attribute__((ext_vector_type(2)))  _Float16 half2v;
typedef __attribute__((ext_vector_type(16))) float    f32x16;
typedef __attribute__((ext_vector_type(2)))  float    v2f;

union H8 { half8 v; half2v p[4]; };
struct AB { half8 hi, lo; };
struct H2 { _Float16 hi, lo; };

__device__ __forceinline__ v2f splat(float v) { v2f r; r.x = v; r.y = v; return r; }

__device__ __forceinline__ v2f vfma(v2f a, v2f b, v2f c) {
    return __builtin_elementwise_fma(a, b, c);
}

__device__ __forceinline__ v2f exp2v(v2f a) {
    v2f r;
    r.x = __builtin_amdgcn_exp2f(a.x);
    r.y = __builtin_amdgcn_exp2f(a.y);
    return r;
}

__device__ __forceinline__ half2v pkrtz(float a, float b) {
    return __builtin_bit_cast(half2v, __builtin_amdgcn_cvt_pkrtz(a, b));
}

// scalar split (build_A only — once per phase, off the hot loop), RNE
__device__ __forceinline__ H2 split1(float v) {
    H2 r;
    r.hi = (_Float16)v;
    r.lo = (_Float16)(v - (float)r.hi);
    return r;
}

// hot-path split: hi = rtz(v); lo = rtz(v - hi). Residual is Sterbenz-exact;
// hi+lo reconstructs to ~2^-21 rel.
__device__ __forceinline__ void split_pair_v(v2f ab, half2v& hi, half2v& lo) {
    hi = pkrtz(ab.x, ab.y);
    v2f hc; hc.x = (float)hi.x; hc.y = (float)hi.y;
    const v2f res = ab - hc;
    lo = pkrtz(res.x, res.y);
}

// Quad-batched reciprocal: 1 v_rcp for FOUR values.
__device__ __forceinline__ void quad_inv(const v2f d[2], v2f inv[2]) {
    const v2f p2 = d[0] * d[1];
    const float r = __builtin_amdgcn_rcpf(p2.x * p2.y);
    const v2f t = splat(r) * p2;
    v2f ts; ts.x = t.y; ts.y = t.x;
    inv[0] = ts * d[1];
    inv[1] = ts * d[0];
}

// A operand, built once per phase. k-row ordering makes B's per-lane pattern
// IDENTICAL for both half-waves:
//   B rows (half p, lane-local): k=8p+{0..7} = {x0, x1, h[4p+0..4p+3], 1, 0}
//   A rows: p0: {Wih[m][0], Wih[m][1], Whh[m][0..3], bias[m], 0}
//           p1: {0,         0,         Whh[m][4..7], 0,       0}
// exp2 prescale folded into A: i/f/o rows scaled by -log2(e), g rows by
// -2*log2(e), so the MFMA output feeds v_exp_f32 directly.
__device__ __forceinline__ AB build_A(int m, int half_,
    const float* __restrict__ Wih, const float* __restrict__ Whh,
    const float* __restrict__ bih, const float* __restrict__ bhh)
{
    const float k = ((m >> 3) == 2) ? (-2.0f * LOG2E) : (-LOG2E);
    float w[8];
    if (half_ == 0) {
        w[0] = Wih[m * 2 + 0] * k;
        w[1] = Wih[m * 2 + 1] * k;
        w[2] = Whh[m * 8 + 0] * k;
        w[3] = Whh[m * 8 + 1] * k;
        w[4] = Whh[m * 8 + 2] * k;
        w[5] = Whh[m * 8 + 3] * k;
        w[6] = (bih[m] + bhh[m]) * k;
        w[7] = 0.0f;
    } else {
        w[0] = 0.0f;
        w[1] = 0.0f;
        w[2] = Whh[m * 8 + 4] * k;
        w[3] = Whh[m * 8 + 5] * k;
        w[4] = Whh[m * 8 + 6] * k;
        w[5] = Whh[m * 8 + 7] * k;
        w[6] = 0.0f;
        w[7] = 0.0f;
    }
    AB r;
#pragma unroll
    for (int i = 0; i < 8; ++i) {
        const H2 s = split1(w[i]);
        r.hi[i] = s.hi;
        r.lo[i] = s.lo;
    }
    return r;
}

// B operand: 3 packed splits + constant tail.
__device__ __forceinline__ AB build_B(v2f x01, const v2f h[2]) {
    H8 hi, lo;
    split_pair_v(x01, hi.p[0], lo.p[0]);
    split_pair_v(h[0], hi.p[1], lo.p[1]);
    split_pair_v(h[1], hi.p[2], lo.p[2]);
    const half2v one0 = {(_Float16)1.0f, (_Float16)0.0f};
    const half2v zz   = {(_Float16)0.0f, (_Float16)0.0f};
    hi.p[3] = one0;
    lo.p[3] = zz;
    AB r; r.hi = hi.v; r.lo = lo.v;
    return r;
}

// 3-MFMA hi/lo product into a fresh acc (Z is a loop-invariant zero tuple).
__device__ __forceinline__ f32x16 mfma3(const AB& A, const AB& B, const f32x16& Z) {
    f32x16 acc = __builtin_amdgcn_mfma_f32_32x32x16_f16(A.hi, B.hi, Z, 0, 0, 0);
    acc = __builtin_amdgcn_mfma_f32_32x32x16_f16(A.hi, B.lo, acc, 0, 0, 0);
    acc = __builtin_amdgcn_mfma_f32_32x32x16_f16(A.lo, B.hi, acc, 0, 0, 0);
    return acc;
}

// Pointwise LSTM combine, pair-grouped (units {0,1} and {2,3} per lane).
// acc holds exp2-ready args (scale folded into A):
//   ei = 2^acc_i = e^-preact_i, eg = 2^acc_g = e^-2*preact_g
//   sigma = 1/(1+ei), tanh = (1-eg)/(1+eg)
//   cn = (tg*uf + c*ui*vg) / (uf*ui*vg)   ; h = (1-ec)/(uo*(1+ec))
// Reciprocals quad-batched: 2 v_rcp per step total.
__device__ __forceinline__ void lstm_pointwise(const f32x16& acc, v2f c[2], v2f h[2]) {
    const v2f vone = splat(1.0f);
    v2f num1[2], den1[2], uo[2];
#pragma unroll
    for (int p = 0; p < 2; ++p) {
        v2f ai, af, ag, ao;
        ai.x = acc[2 * p + 0];  ai.y = acc[2 * p + 1];
        af.x = acc[4 + 2 * p];  af.y = acc[5 + 2 * p];
        ag.x = acc[8 + 2 * p];  ag.y = acc[9 + 2 * p];
        ao.x = acc[12 + 2 * p]; ao.y = acc[13 + 2 * p];
        const v2f ei = exp2v(ai);
        const v2f ef = exp2v(af);
        const v2f eg = exp2v(ag);
        const v2f eo = exp2v(ao);
        const v2f ui = ei + vone;
        const v2f uf = ef + vone;
        const v2f vg = eg + vone;
        const v2f tg = vone - eg;
        const v2f uiv = ui * vg;
        num1[p] = vfma(tg, uf, c[p] * uiv);
        den1[p] = uf * uiv;
        uo[p] = eo + vone;
    }
    v2f inv1[2];
    quad_inv(den1, inv1);

    v2f den2[2], tc[2];
#pragma unroll
    for (int p = 0; p < 2; ++p) {
        const v2f cn = num1[p] * inv1[p];
        c[p] = cn;
        const v2f s0 = cn * splat(-2.0f * LOG2E);
        v2f s; s.x = fminf(s0.x, ECLAMP); s.y = fminf(s0.y, ECLAMP);
        const v2f ec = exp2v(s);
        den2[p] = uo[p] * (ec + vone);
        tc[p] = vone - ec;
    }
    v2f inv2[2];
    quad_inv(den2, inv2);
    h[0] = tc[0] * inv2[0];
    h[1] = tc[1] * inv2[1];
}

__global__ __launch_bounds__(BLOCK) void MYLSTM_88201448390683_kernel(
    const float* __restrict__ obs,    // (OBS_LEN, B, 2)
    const float* __restrict__ h0,     // (B, HID)
    const float* __restrict__ c0,     // (B, HID)
    const float* __restrict__ Wih_t, const float* __restrict__ Whh_t,
    const float* __restrict__ bih_t, const float* __restrict__ bhh_t,
    const float* __restrict__ Wih_p, const float* __restrict__ Whh_p,
    const float* __restrict__ bih_p, const float* __restrict__ bhh_p,
    const float* __restrict__ Wp,     // (2, HID)
    const float* __restrict__ bp,     // (2,)
    float* __restrict__ out,          // (PRED_LEN, B, 2)
    int B)
{
    const int lane = threadIdx.x & 63;
    const int wid  = threadIdx.x >> 6;
    const int e    = lane & 31;         // element column; also gate row m for A
    const int half = lane >> 5;

    // Two independent element streams per wave (r3 post-mortem: ~20% issue-idle
    // from dependency stalls; dual streams give cross-stream ILP while keeping
    // per-element math bit-identical to r3).
    int eg0 = blockIdx.x * ELEMS_PER_BLOCK + wid * 64 + e;
    int eg1 = eg0 + 32;
    const bool ok0 = eg0 < B;
    const bool ok1 = eg1 < B;
    if (!ok0) eg0 = 0;
    if (!ok1) eg1 = 0;

    const f32x16 kZero = {};

    // lane owns units 4*half .. 4*half+3 of its element (C/D layout:
    // row = (reg&3) + 8*(reg>>2) + 4*half => unit=(reg&3)+4*half, gate=reg>>2)
    v2f hA[2], cA[2], hB[2], cB[2];
    {
        const float4 hv0 = *reinterpret_cast<const float4*>(h0 + (size_t)eg0 * HID + half * 4);
        const float4 cv0 = *reinterpret_cast<const float4*>(c0 + (size_t)eg0 * HID + half * 4);
        const float4 hv1 = *reinterpret_cast<const float4*>(h0 + (size_t)eg1 * HID + half * 4);
        const float4 cv1 = *reinterpret_cast<const float4*>(c0 + (size_t)eg1 * HID + half * 4);
        hA[0].x = hv0.x; hA[0].y = hv0.y; hA[1].x = hv0.z; hA[1].y = hv0.w;
        cA[0].x = cv0.x; cA[0].y = cv0.y; cA[1].x = cv0.z; cA[1].y = cv0.w;
        hB[0].x = hv1.x; hB[0].y = hv1.y; hB[1].x = hv1.z; hB[1].y = hv1.w;
        cB[0].x = cv1.x; cB[0].y = cv1.y; cB[1].x = cv1.z; cB[1].y = cv1.w;
    }

    // ---- encoder ----
    {
        const AB Aenc = build_A(e, half, Wih_t, Whh_t, bih_t, bhh_t);
        const float* op = obs + (size_t)eg0 * 2;
        const long doff = ((long)eg1 - (long)eg0) * 2;   // 64 normally, <=0 at tail
        const size_t ostride = (size_t)B * 2;
#pragma unroll 1
        for (int t = 0; t < OBS_LEN; ++t) {
            const v2f xv0 = *reinterpret_cast<const v2f*>(op);
            const v2f xv1 = *reinterpret_cast<const v2f*>(op + doff);
            op += ostride;
            v2f xr0, xr1;
            xr0.x = fmaxf(xv0.x, 0.0f); xr0.y = fmaxf(xv0.y, 0.0f);
            xr1.x = fmaxf(xv1.x, 0.0f); xr1.y = fmaxf(xv1.y, 0.0f);
            // issue order: B-build A, MFMA A, B-build B, MFMA B, pw A, pw B —
            // stream A's pointwise overlaps stream B's in-flight MFMAs.
            const AB Bv0 = build_B(xr0, hA);
            const f32x16 accA = mfma3(Aenc, Bv0, kZero);
            const AB Bv1 = build_B(xr1, hB);
            const f32x16 accB = mfma3(Aenc, Bv1, kZero);
            lstm_pointwise(accA, cA, hA);
            lstm_pointwise(accB, cB, hB);
        }
    }

    // ---- decoder ----
    const AB Adec = build_A(e, half, Wih_p, Whh_p, bih_p, bhh_p);
    cA[0] = splat(0.0f); cA[1] = splat(0.0f);
    cB[0] = splat(0.0f); cB[1] = splat(0.0f);

    v2f wa[2], wb[2];
    wa[0].x = Wp[4 * half + 0];       wa[0].y = Wp[4 * half + 1];
    wa[1].x = Wp[4 * half + 2];       wa[1].y = Wp[4 * half + 3];
    wb[0].x = Wp[HID + 4 * half + 0]; wb[0].y = Wp[HID + 4 * half + 1];
    wb[1].x = Wp[HID + 4 * half + 2]; wb[1].y = Wp[HID + 4 * half + 3];
    const float bp0 = bp[0], bp1 = bp[1];

    v2f xA = splat(0.0f), xB = splat(0.0f);
#pragma unroll 1
    for (int t = 0; t < PRED_LEN; ++t) {
        const AB Bv0 = build_B(xA, hA);
        const f32x16 accA = mfma3(Adec, Bv0, kZero);
        const AB Bv1 = build_B(xB, hB);
        const f32x16 accB = mfma3(Adec, Bv1, kZero);
        lstm_pointwise(accA, cA, hA);
        lstm_pointwise(accB, cB, hB);

        // out = tanh(h @ Wp.T + bp) * SCALE ; h split across lane pairs
        const v2f q0A = vfma(wa[1], hA[1], wa[0] * hA[0]);
        const v2f q1A = vfma(wb[1], hA[1], wb[0] * hA[0]);
        const v2f q0B = vfma(wa[1], hB[1], wa[0] * hB[0]);
        const v2f q1B = vfma(wb[1], hB[1], wb[0] * hB[0]);
        float a0A = q0A.x + q0A.y, a1A = q1A.x + q1A.y;
        float a0B = q0B.x + q0B.y, a1B = q1B.x + q1B.y;
        a0A += __shfl_xor(a0A, 32);
        a1A += __shfl_xor(a1A, 32);
        a0B += __shfl_xor(a0B, 32);
        a1B += __shfl_xor(a1B, 32);
        v2f avA; avA.x = a0A + bp0; avA.y = a1A + bp1;
        v2f avB; avB.x = a0B + bp0; avB.y = a1B + bp1;
        // tanh via rational form, one rcp per stream pair
        const v2f evA = exp2v(avA * splat(-2.0f * LOG2E));
        const v2f evB = exp2v(avB * splat(-2.0f * LOG2E));
        const v2f denA = evA + splat(1.0f);
        const v2f denB = evB + splat(1.0f);
        const float rA = __builtin_amdgcn_rcpf(denA.x * denA.y);
        const float rB = __builtin_amdgcn_rcpf(denB.x * denB.y);
        v2f dsA; dsA.x = denA.y; dsA.y = denA.x;
        v2f dsB; dsB.x = denB.y; dsB.y = denB.x;
        const v2f invA = splat(rA) * dsA;
        const v2f invB = splat(rB) * dsB;
        xA = ((splat(1.0f) - evA) * invA) * splat(SCALE);
        xB = ((splat(1.0f) - evB) * invB) * splat(SCALE);
        if (!half) {
            if (ok0) *reinterpret_cast<float2*>(out + ((size_t)t * B + eg0) * 2) = make_float2(xA.x, xA.y);
            if (ok1) *reinterpret_cast<float2*>(out + ((size_t)t * B + eg1) * 2) = make_float2(xB.x, xB.y);
        }
    }
}

extern "C" void kernel_launch(void* const* d_in, const int* in_sizes, int n_in,
                              void* d_out, int out_size, void* d_ws, size_t ws_size,
                              hipStream_t stream) {
    const float* obs   = (const float*)d_in[0];
    const float* h0    = (const float*)d_in[1];
    const float* c0    = (const float*)d_in[2];
    const float* Wih_t = (const float*)d_in[3];
    const float* Whh_t = (const float*)d_in[4];
    const float* bih_t = (const float*)d_in[5];
    const float* bhh_t = (const float*)d_in[6];
    const float* Wih_p = (const float*)d_in[7];
    const float* Whh_p = (const float*)d_in[8];
    const float* bih_p = (const float*)d_in[9];
    const float* bhh_p = (const float*)d_in[10];
    const float* Wp    = (const float*)d_in[11];
    const float* bp    = (const float*)d_in[12];
    float* out = (float*)d_out;

    const int B = in_sizes[1] / HID;  // h0 is (B, HID)
    const int grid = (B + ELEMS_PER_BLOCK - 1) / ELEMS_PER_BLOCK;

    hipLaunchKernelGGL(MYLSTM_88201448390683_kernel, dim3(grid), dim3(BLOCK), 0, stream,
                       obs, h0, c0,
                       Wih_t, Whh_t, bih_t, bhh_t,
                       Wih_p, Whh_p, bih_p, bhh_p,
                       Wp, bp, out, B);
}

// Round 5
// 334.306 us; speedup vs baseline: 1.0387x; 1.0387x over previous
//
#include <hip/hip_runtime.h>

#define HID 8
#define OBS_LEN 8
#define PRED_LEN 12
#define SCALE 4.4f
#define BLOCK 256
#define ELEMS_PER_BLOCK 128   // 4 waves * 32 elems per wave

#define LOG2E 1.44269504f
// exp2-arg clamp on the cn (cell) path only (|c| grows ~1/step): cap at 16.
// Gate preacts are structurally bounded -> no clamp needed there.
#define ECLAMP 16.0f

typedef __attribute__((ext_vector_type(8)))  _Float16 half8;
typedef __attribute__((ext_vector_type(2)))  _Float16 half2v;
typedef __attribute__((ext_vector_type(16))) float    f32x16;
typedef __attribute__((ext_vector_type(2)))  float    v2f;

union H8 { half8 v; half2v p[4]; };
struct AB { half8 hi, lo; };
struct H2 { _Float16 hi, lo; };

__device__ __forceinline__ v2f splat(float v) { v2f r; r.x = v; r.y = v; return r; }

__device__ __forceinline__ v2f vfma(v2f a, v2f b, v2f c) {
    return __builtin_elementwise_fma(a, b, c);
}

__device__ __forceinline__ v2f exp2v(v2f a) {
    v2f r;
    r.x = __builtin_amdgcn_exp2f(a.x);
    r.y = __builtin_amdgcn_exp2f(a.y);
    return r;
}

__device__ __forceinline__ half2v pkrtz(float a, float b) {
    return __builtin_bit_cast(half2v, __builtin_amdgcn_cvt_pkrtz(a, b));
}

// scalar split (build_A only — once per phase, off the hot loop), RNE
__device__ __forceinline__ H2 split1(float v) {
    H2 r;
    r.hi = (_Float16)v;
    r.lo = (_Float16)(v - (float)r.hi);
    return r;
}

// hot-path split: hi = rtz(v); lo = rtz(v - hi). Residual is Sterbenz-exact;
// hi+lo reconstructs to ~2^-21 rel.
__device__ __forceinline__ void split_pair_v(v2f ab, half2v& hi, half2v& lo) {
    hi = pkrtz(ab.x, ab.y);
    v2f hc; hc.x = (float)hi.x; hc.y = (float)hi.y;
    const v2f res = ab - hc;
    lo = pkrtz(res.x, res.y);
}

// Quad-batched reciprocal: 1 v_rcp for FOUR values (beats 4 direct rcps at
// T_trans ~10cyc: 18 mul + 1 rcp = ~46cyc vs 4 rcp = ~40cyc + accuracy same;
// kept because it also halves trans-queue pressure).
__device__ __forceinline__ void quad_inv(const v2f d[2], v2f inv[2]) {
    const v2f p2 = d[0] * d[1];
    const float r = __builtin_amdgcn_rcpf(p2.x * p2.y);
    const v2f t = splat(r) * p2;
    v2f ts; ts.x = t.y; ts.y = t.x;
    inv[0] = ts * d[1];
    inv[1] = ts * d[0];
}

// A operand, built once per phase. k-row ordering makes B's per-lane pattern
// IDENTICAL for both half-waves:
//   B rows (half p, lane-local): k=8p+{0..7} = {x0, x1, h[4p+0..4p+3], 1, 0}
//   A rows: p0: {Wih[m][0], Wih[m][1], Whh[m][0..3], bias[m], 0}
//           p1: {0,         0,         Whh[m][4..7], 0,       0}
// exp2 prescale folded into A: i/f/o rows scaled by -log2(e), g rows by
// -2*log2(e), so the MFMA output feeds v_exp_f32 directly.
__device__ __forceinline__ AB build_A(int m, int half_,
    const float* __restrict__ Wih, const float* __restrict__ Whh,
    const float* __restrict__ bih, const float* __restrict__ bhh)
{
    const float k = ((m >> 3) == 2) ? (-2.0f * LOG2E) : (-LOG2E);
    float w[8];
    if (half_ == 0) {
        w[0] = Wih[m * 2 + 0] * k;
        w[1] = Wih[m * 2 + 1] * k;
        w[2] = Whh[m * 8 + 0] * k;
        w[3] = Whh[m * 8 + 1] * k;
        w[4] = Whh[m * 8 + 2] * k;
        w[5] = Whh[m * 8 + 3] * k;
        w[6] = (bih[m] + bhh[m]) * k;
        w[7] = 0.0f;
    } else {
        w[0] = 0.0f;
        w[1] = 0.0f;
        w[2] = Whh[m * 8 + 4] * k;
        w[3] = Whh[m * 8 + 5] * k;
        w[4] = Whh[m * 8 + 6] * k;
        w[5] = Whh[m * 8 + 7] * k;
        w[6] = 0.0f;
        w[7] = 0.0f;
    }
    AB r;
#pragma unroll
    for (int i = 0; i < 8; ++i) {
        const H2 s = split1(w[i]);
        r.hi[i] = s.hi;
        r.lo[i] = s.lo;
    }
    return r;
}

// B operand: 3 packed splits + constant tail.
__device__ __forceinline__ AB build_B(v2f x01, const v2f h[2]) {
    H8 hi, lo;
    split_pair_v(x01, hi.p[0], lo.p[0]);
    split_pair_v(h[0], hi.p[1], lo.p[1]);
    split_pair_v(h[1], hi.p[2], lo.p[2]);
    const half2v one0 = {(_Float16)1.0f, (_Float16)0.0f};
    const half2v zz   = {(_Float16)0.0f, (_Float16)0.0f};
    hi.p[3] = one0;
    lo.p[3] = zz;
    AB r; r.hi = hi.v; r.lo = lo.v;
    return r;
}

// Pointwise LSTM combine, pair-grouped (units {0,1} and {2,3} per lane).
// acc holds exp2-ready args (scale folded into A):
//   ei = 2^acc_i = e^-preact_i, eg = 2^acc_g = e^-2*preact_g
//   sigma = 1/(1+ei), tanh = (1-eg)/(1+eg)
//   cn = (tg*uf + c*ui*vg) / (uf*ui*vg)   ; h = (1-ec)/(uo*(1+ec))
// Strength-reduced (r5 diet): ui*vg = fma(ei,vg,vg); uo*(1+ec) = fma(ec,uo,uo);
// (1-ec)*inv2 = fma(-ec,inv2,inv2) — each kills a mul/add pair via the free
// VOP3 neg modifier. Value-identical to within 1-ulp fma rounding.
// Reciprocals quad-batched: 2 v_rcp per step total.
__device__ __forceinline__ void lstm_pointwise(const f32x16& acc, v2f c[2], v2f h[2]) {
    const v2f vone = splat(1.0f);
    v2f num1[2], den1[2], uo[2];
#pragma unroll
    for (int p = 0; p < 2; ++p) {
        v2f ai, af, ag, ao;
        ai.x = acc[2 * p + 0];  ai.y = acc[2 * p + 1];
        af.x = acc[4 + 2 * p];  af.y = acc[5 + 2 * p];
        ag.x = acc[8 + 2 * p];  ag.y = acc[9 + 2 * p];
        ao.x = acc[12 + 2 * p]; ao.y = acc[13 + 2 * p];
        const v2f ei = exp2v(ai);
        const v2f ef = exp2v(af);
        const v2f eg = exp2v(ag);
        const v2f eo = exp2v(ao);
        const v2f uf = ef + vone;
        const v2f vg = eg + vone;
        const v2f tg = vone - eg;
        const v2f uiv = vfma(ei, vg, vg);          // (1+ei)*vg
        num1[p] = vfma(tg, uf, c[p] * uiv);
        den1[p] = uf * uiv;
        uo[p] = eo + vone;
    }
    v2f inv1[2];
    quad_inv(den1, inv1);

    v2f den2[2], ecs[2];
#pragma unroll
    for (int p = 0; p < 2; ++p) {
        const v2f cn = num1[p] * inv1[p];
        c[p] = cn;
        const v2f s0 = cn * splat(-2.0f * LOG2E);
        v2f s; s.x = fminf(s0.x, ECLAMP); s.y = fminf(s0.y, ECLAMP);
        const v2f ec = exp2v(s);
        den2[p] = vfma(ec, uo[p], uo[p]);          // uo*(1+ec)
        ecs[p] = ec;
    }
    v2f inv2[2];
    quad_inv(den2, inv2);
    h[0] = vfma(-ecs[0], inv2[0], inv2[0]);        // (1-ec)*inv2
    h[1] = vfma(-ecs[1], inv2[1], inv2[1]);
}

// Z is a loop-invariant zero tuple: MFMA reads it as C and writes a fresh D,
// eliminating 16 v_mov acc-zeroing per step.
__device__ __forceinline__ void lstm_mfma_step(const AB& A, const AB& B, const f32x16& Z,
                                               v2f c[2], v2f h[2]) {
    f32x16 acc = __builtin_amdgcn_mfma_f32_32x32x16_f16(A.hi, B.hi, Z, 0, 0, 0);
    acc = __builtin_amdgcn_mfma_f32_32x32x16_f16(A.hi, B.lo, acc, 0, 0, 0);
    acc = __builtin_amdgcn_mfma_f32_32x32x16_f16(A.lo, B.hi, acc, 0, 0, 0);
    lstm_pointwise(acc, c, h);
}

__global__ __launch_bounds__(BLOCK) void MYLSTM_88201448390683_kernel(
    const float* __restrict__ obs,    // (OBS_LEN, B, 2)
    const float* __restrict__ h0,     // (B, HID)
    const float* __restrict__ c0,     // (B, HID)
    const float* __restrict__ Wih_t, const float* __restrict__ Whh_t,
    const float* __restrict__ bih_t, const float* __restrict__ bhh_t,
    const float* __restrict__ Wih_p, const float* __restrict__ Whh_p,
    const float* __restrict__ bih_p, const float* __restrict__ bhh_p,
    const float* __restrict__ Wp,     // (2, HID)
    const float* __restrict__ bp,     // (2,)
    float* __restrict__ out,          // (PRED_LEN, B, 2)
    int B)
{
    const int lane = threadIdx.x & 63;
    const int wid  = threadIdx.x >> 6;
    const int e    = lane & 31;         // element column; also gate row m for A
    const int half = lane >> 5;

    int eg = blockIdx.x * ELEMS_PER_BLOCK + wid * 32 + e;
    const bool ok = eg < B;
    if (!ok) eg = 0;

    const f32x16 kZero = {};

    // lane owns units 4*half .. 4*half+3 of element eg (C/D layout:
    // row = (reg&3) + 8*(reg>>2) + 4*half => unit=(reg&3)+4*half, gate=reg>>2)
    v2f h[2], c[2];
    {
        const float4 hv = *reinterpret_cast<const float4*>(h0 + (size_t)eg * HID + half * 4);
        const float4 cv = *reinterpret_cast<const float4*>(c0 + (size_t)eg * HID + half * 4);
        h[0].x = hv.x; h[0].y = hv.y; h[1].x = hv.z; h[1].y = hv.w;
        c[0].x = cv.x; c[0].y = cv.y; c[1].x = cv.z; c[1].y = cv.w;
    }

    // ---- encoder ----
    {
        const AB Aenc = build_A(e, half, Wih_t, Whh_t, bih_t, bhh_t);
        const float* op = obs + (size_t)eg * 2;
        const size_t ostride = (size_t)B * 2;
#pragma unroll 1
        for (int t = 0; t < OBS_LEN; ++t) {
            // both halves load the same element's obs (same address; L1 serves it)
            const v2f xv = *reinterpret_cast<const v2f*>(op);
            op += ostride;
            v2f xr; xr.x = fmaxf(xv.x, 0.0f); xr.y = fmaxf(xv.y, 0.0f);
            const AB Bv = build_B(xr, h);
            lstm_mfma_step(Aenc, Bv, kZero, c, h);
        }
    }

    // ---- decoder ----
    const AB Adec = build_A(e, half, Wih_p, Whh_p, bih_p, bhh_p);
    c[0] = splat(0.0f);
    c[1] = splat(0.0f);

    v2f wa[2], wb[2];
    wa[0].x = Wp[4 * half + 0];       wa[0].y = Wp[4 * half + 1];
    wa[1].x = Wp[4 * half + 2];       wa[1].y = Wp[4 * half + 3];
    wb[0].x = Wp[HID + 4 * half + 0]; wb[0].y = Wp[HID + 4 * half + 1];
    wb[1].x = Wp[HID + 4 * half + 2]; wb[1].y = Wp[HID + 4 * half + 3];
    // bias baked into HALF 0's fma accumulator: after the xor-32 sum both
    // halves receive it exactly once (a = p0+bp [half0] + p1 [half1]).
    v2f b0v, b1v;
    b0v.x = half ? 0.0f : bp[0]; b0v.y = 0.0f;
    b1v.x = half ? 0.0f : bp[1]; b1v.y = 0.0f;

    v2f x01 = splat(0.0f);
#pragma unroll 1
    for (int t = 0; t < PRED_LEN; ++t) {
        const AB Bv = build_B(x01, h);
        lstm_mfma_step(Adec, Bv, kZero, c, h);
        // out = tanh(h @ Wp.T + bp) * SCALE ; h split across lane pairs
        const v2f q0 = vfma(wa[1], h[1], vfma(wa[0], h[0], b0v));
        const v2f q1 = vfma(wb[1], h[1], vfma(wb[0], h[0], b1v));
        float a0 = q0.x + q0.y;
        float a1 = q1.x + q1.y;
        a0 += __shfl_xor(a0, 32);   // both halves now hold the full biased sums
        a1 += __shfl_xor(a1, 32);
        v2f av; av.x = a0; av.y = a1;
        // tanh via rational form, one rcp for the pair
        const v2f ev = exp2v(av * splat(-2.0f * LOG2E));
        const v2f den = ev + splat(1.0f);
        const float r = __builtin_amdgcn_rcpf(den.x * den.y);
        v2f ds; ds.x = den.y; ds.y = den.x;
        const v2f invv = splat(r) * ds;
        const v2f tn = splat(1.0f) - ev;
        x01 = (tn * invv) * splat(SCALE);
        if (!half && ok) {
            *reinterpret_cast<float2*>(out + ((size_t)t * B + eg) * 2) = make_float2(x01.x, x01.y);
        }
    }
}

extern "C" void kernel_launch(void* const* d_in, const int* in_sizes, int n_in,
                              void* d_out, int out_size, void* d_ws, size_t ws_size,
                              hipStream_t stream) {
    const float* obs   = (const float*)d_in[0];
    const float* h0    = (const float*)d_in[1];
    const float* c0    = (const float*)d_in[2];
    const float* Wih_t = (const float*)d_in[3];
    const float* Whh_t = (const float*)d_in[4];
    const float* bih_t = (const float*)d_in[5];
    const float* bhh_t = (const float*)d_in[6];
    const float* Wih_p = (const float*)d_in[7];
    const float* Whh_p = (const float*)d_in[8];
    const float* bih_p = (const float*)d_in[9];
    const float* bhh_p = (const float*)d_in[10];
    const float* Wp    = (const float*)d_in[11];
    const float* bp    = (const float*)d_in[12];
    float* out = (float*)d_out;

    const int B = in_sizes[1] / HID;  // h0 is (B, HID)
    const int grid = (B + ELEMS_PER_BLOCK - 1) / ELEMS_PER_BLOCK;

    hipLaunchKernelGGL(MYLSTM_88201448390683_kernel, dim3(grid), dim3(BLOCK), 0, stream,
                       obs, h0, c0,
                       Wih_t, Whh_t, bih_t, bhh_t,
                       Wih_p, Whh_p, bih_p, bhh_p,
                       Wp, bp, out, B);
}

// Round 6
// 329.581 us; speedup vs baseline: 1.0536x; 1.0143x over previous
//
#include <hip/hip_runtime.h>

#define HID 8
#define OBS_LEN 8
#define PRED_LEN 12
#define SCALE 4.4f
#define BLOCK 256
#define ELEMS_PER_BLOCK 128   // 4 waves * 32 elems per wave

#define LOG2E 1.44269504f
// exp2-arg clamp on the cn (cell) path only (|c| grows ~1/step): cap at 16.
// Gate preacts are structurally bounded -> no clamp needed there.
#define ECLAMP 16.0f

typedef __attribute__((ext_vector_type(8)))  _Float16 half8;
typedef __attribute__((ext_vector_type(2)))  _Float16 half2v;
typedef __attribute__((ext_vector_type(16))) float    f32x16;
typedef __attribute__((ext_vector_type(2)))  float    v2f;

union H8 { half8 v; half2v p[4]; };
struct AB { half8 hi, lo; };
struct H2 { _Float16 hi, lo; };

__device__ __forceinline__ v2f splat(float v) { v2f r; r.x = v; r.y = v; return r; }

__device__ __forceinline__ v2f vfma(v2f a, v2f b, v2f c) {
    return __builtin_elementwise_fma(a, b, c);
}

__device__ __forceinline__ v2f exp2v(v2f a) {
    v2f r;
    r.x = __builtin_amdgcn_exp2f(a.x);
    r.y = __builtin_amdgcn_exp2f(a.y);
    return r;
}

__device__ __forceinline__ half2v pkrtz(float a, float b) {
    return __builtin_bit_cast(half2v, __builtin_amdgcn_cvt_pkrtz(a, b));
}

// RNE pack (2 v_cvt + pack) — unbiased fp16 for the steady-state h path
// (RTZ's systematic toward-zero bias would accumulate through the recurrence).
__device__ __forceinline__ half2v rne2(v2f v) {
    half2v r; r.x = (_Float16)v.x; r.y = (_Float16)v.y; return r;
}

// scalar split (build_A only — once per phase, off the hot loop), RNE
__device__ __forceinline__ H2 split1(float v) {
    H2 r;
    r.hi = (_Float16)v;
    r.lo = (_Float16)(v - (float)r.hi);
    return r;
}

// Quad-batched reciprocal: 1 v_rcp for FOUR values.
__device__ __forceinline__ void quad_inv(const v2f d[2], v2f inv[2]) {
    const v2f p2 = d[0] * d[1];
    const float r = __builtin_amdgcn_rcpf(p2.x * p2.y);
    const v2f t = splat(r) * p2;
    v2f ts; ts.x = t.y; ts.y = t.x;
    inv[0] = ts * d[1];
    inv[1] = ts * d[0];
}

// A operand, built once per phase.
//   B rows (half p, lane-local):
//     p0: k0-7  = {x0hi, x1hi, h[0..3] (fp16), 1, 0}
//     p1: k8-15 = {x0lo, x1lo, h[4..7] (fp16), 1, 0}   <- x RESIDUAL in the
//       previously-dead p1 rows 0,1 (r6 spare-K-row trick): with A carrying
//       Wih on BOTH halves' x-rows, A.hi*B + A.lo*B reproduces the exact
//       (Whi+Wlo)(xhi+xlo) product for x and bias; only h is fp16-RNE.
//   A rows: p0: {Wih[m][0..1], Whh[m][0..3], bias[m], 0}
//           p1: {Wih[m][0..1], Whh[m][4..7], 0,       0}
// exp2 prescale folded into A: i/f/o rows scaled by -log2(e), g rows by
// -2*log2(e), so the MFMA output feeds v_exp_f32 directly.
__device__ __forceinline__ AB build_A(int m, int half_,
    const float* __restrict__ Wih, const float* __restrict__ Whh,
    const float* __restrict__ bih, const float* __restrict__ bhh)
{
    const float k = ((m >> 3) == 2) ? (-2.0f * LOG2E) : (-LOG2E);
    float w[8];
    w[0] = Wih[m * 2 + 0] * k;      // both halves: p0 pairs with xhi, p1 with xlo
    w[1] = Wih[m * 2 + 1] * k;
    if (half_ == 0) {
        w[2] = Whh[m * 8 + 0] * k;
        w[3] = Whh[m * 8 + 1] * k;
        w[4] = Whh[m * 8 + 2] * k;
        w[5] = Whh[m * 8 + 3] * k;
        w[6] = (bih[m] + bhh[m]) * k;
    } else {
        w[2] = Whh[m * 8 + 4] * k;
        w[3] = Whh[m * 8 + 5] * k;
        w[4] = Whh[m * 8 + 6] * k;
        w[5] = Whh[m * 8 + 7] * k;
        w[6] = 0.0f;
    }
    w[7] = 0.0f;
    AB r;
#pragma unroll
    for (int i = 0; i < 8; ++i) {
        const H2 s = split1(w[i]);
        r.hi[i] = s.hi;
        r.lo[i] = s.lo;
    }
    return r;
}

// Steady-state B: exact x (hi/lo across the half select), RNE fp16 h.
__device__ __forceinline__ half8 build_B_hi(v2f x01, const v2f h[2], bool half1) {
    H8 hi;
    const half2v xh = pkrtz(x01.x, x01.y);
    v2f hc; hc.x = (float)xh.x; hc.y = (float)xh.y;
    const v2f res = x01 - hc;           // Sterbenz-exact residual
    const half2v xl = pkrtz(res.x, res.y);
    hi.p[0] = half1 ? xl : xh;          // 1 cndmask (hoisted cmp)
    hi.p[1] = rne2(h[0]);
    hi.p[2] = rne2(h[1]);
    const half2v one0 = {(_Float16)1.0f, (_Float16)0.0f};
    hi.p[3] = one0;
    return hi.v;
}

// Step-0-only h-residual operand (h0 ~ N(0,1) is unbounded; fp16 err on
// |h0|~5 reaches ~2e-3 in preact terms — the one step where the residual
// genuinely matters). Residuals are vs the RNE hi already packed in bh.
__device__ __forceinline__ half8 build_B_lo_h(const v2f h[2], half8 bh) {
    H8 hb; hb.v = bh;
    H8 lo;
    v2f r0; r0.x = h[0].x - (float)hb.p[1].x; r0.y = h[0].y - (float)hb.p[1].y;
    v2f r1; r1.x = h[1].x - (float)hb.p[2].x; r1.y = h[1].y - (float)hb.p[2].y;
    const half2v zz = {(_Float16)0.0f, (_Float16)0.0f};
    lo.p[0] = zz;
    lo.p[1] = pkrtz(r0.x, r0.y);
    lo.p[2] = pkrtz(r1.x, r1.y);
    lo.p[3] = zz;
    return lo.v;
}

// Pointwise LSTM combine, pair-grouped (units {0,1} and {2,3} per lane).
// acc holds exp2-ready args (scale folded into A):
//   ei = 2^acc_i = e^-preact_i, eg = 2^acc_g = e^-2*preact_g
//   sigma = 1/(1+ei), tanh = (1-eg)/(1+eg)
//   cn = (tg*uf + c*ui*vg) / (uf*ui*vg)   ; h = (1-ec)/(uo*(1+ec))
// Strength-reduced: ui*vg = fma(ei,vg,vg); uo*(1+ec) = fma(ec,uo,uo);
// (1-ec)*inv2 = fma(-ec,inv2,inv2). Reciprocals quad-batched: 2 v_rcp/step.
__device__ __forceinline__ void lstm_pointwise(const f32x16& acc, v2f c[2], v2f h[2]) {
    const v2f vone = splat(1.0f);
    v2f num1[2], den1[2], uo[2];
#pragma unroll
    for (int p = 0; p < 2; ++p) {
        v2f ai, af, ag, ao;
        ai.x = acc[2 * p + 0];  ai.y = acc[2 * p + 1];
        af.x = acc[4 + 2 * p];  af.y = acc[5 + 2 * p];
        ag.x = acc[8 + 2 * p];  ag.y = acc[9 + 2 * p];
        ao.x = acc[12 + 2 * p]; ao.y = acc[13 + 2 * p];
        const v2f ei = exp2v(ai);
        const v2f ef = exp2v(af);
        const v2f eg = exp2v(ag);
        const v2f eo = exp2v(ao);
        const v2f uf = ef + vone;
        const v2f vg = eg + vone;
        const v2f tg = vone - eg;
        const v2f uiv = vfma(ei, vg, vg);          // (1+ei)*vg
        num1[p] = vfma(tg, uf, c[p] * uiv);
        den1[p] = uf * uiv;
        uo[p] = eo + vone;
    }
    v2f inv1[2];
    quad_inv(den1, inv1);

    v2f den2[2], ecs[2];
#pragma unroll
    for (int p = 0; p < 2; ++p) {
        const v2f cn = num1[p] * inv1[p];
        c[p] = cn;
        const v2f s0 = cn * splat(-2.0f * LOG2E);
        v2f s; s.x = fminf(s0.x, ECLAMP); s.y = fminf(s0.y, ECLAMP);
        const v2f ec = exp2v(s);
        den2[p] = vfma(ec, uo[p], uo[p]);          // uo*(1+ec)
        ecs[p] = ec;
    }
    v2f inv2[2];
    quad_inv(den2, inv2);
    h[0] = vfma(-ecs[0], inv2[0], inv2[0]);        // (1-ec)*inv2
    h[1] = vfma(-ecs[1], inv2[1], inv2[1]);
}

// Steady-state step: 2 MFMAs (A.hi + A.lo against the same B).
__device__ __forceinline__ void lstm_step2(const AB& A, const half8& Bh, const f32x16& Z,
                                           v2f c[2], v2f h[2]) {
    f32x16 acc = __builtin_amdgcn_mfma_f32_32x32x16_f16(A.hi, Bh, Z, 0, 0, 0);
    acc = __builtin_amdgcn_mfma_f32_32x32x16_f16(A.lo, Bh, acc, 0, 0, 0);
    lstm_pointwise(acc, c, h);
}

__global__ __launch_bounds__(BLOCK) void MYLSTM_88201448390683_kernel(
    const float* __restrict__ obs,    // (OBS_LEN, B, 2)
    const float* __restrict__ h0,     // (B, HID)
    const float* __restrict__ c0,     // (B, HID)
    const float* __restrict__ Wih_t, const float* __restrict__ Whh_t,
    const float* __restrict__ bih_t, const float* __restrict__ bhh_t,
    const float* __restrict__ Wih_p, const float* __restrict__ Whh_p,
    const float* __restrict__ bih_p, const float* __restrict__ bhh_p,
    const float* __restrict__ Wp,     // (2, HID)
    const float* __restrict__ bp,     // (2,)
    float* __restrict__ out,          // (PRED_LEN, B, 2)
    int B)
{
    const int lane = threadIdx.x & 63;
    const int wid  = threadIdx.x >> 6;
    const int e    = lane & 31;         // element column; also gate row m for A
    const int half = lane >> 5;
    const bool half1 = half != 0;

    int eg = blockIdx.x * ELEMS_PER_BLOCK + wid * 32 + e;
    const bool ok = eg < B;
    if (!ok) eg = 0;

    const f32x16 kZero = {};

    // lane owns units 4*half .. 4*half+3 of element eg (C/D layout:
    // row = (reg&3) + 8*(reg>>2) + 4*half => unit=(reg&3)+4*half, gate=reg>>2)
    v2f h[2], c[2];
    {
        const float4 hv = *reinterpret_cast<const float4*>(h0 + (size_t)eg * HID + half * 4);
        const float4 cv = *reinterpret_cast<const float4*>(c0 + (size_t)eg * HID + half * 4);
        h[0].x = hv.x; h[0].y = hv.y; h[1].x = hv.z; h[1].y = hv.w;
        c[0].x = cv.x; c[0].y = cv.y; c[1].x = cv.z; c[1].y = cv.w;
    }

    // ---- encoder ----
    {
        const AB Aenc = build_A(e, half, Wih_t, Whh_t, bih_t, bhh_t);
        const float* op = obs + (size_t)eg * 2;
        const size_t ostride = (size_t)B * 2;
        // t = 0: h0 unbounded -> keep the h-residual (3-MFMA) path
        {
            const v2f xv = *reinterpret_cast<const v2f*>(op);
            op += ostride;
            v2f xr; xr.x = fmaxf(xv.x, 0.0f); xr.y = fmaxf(xv.y, 0.0f);
            const half8 Bh = build_B_hi(xr, h, half1);
            const half8 Bl = build_B_lo_h(h, Bh);
            f32x16 acc = __builtin_amdgcn_mfma_f32_32x32x16_f16(Aenc.hi, Bh, kZero, 0, 0, 0);
            acc = __builtin_amdgcn_mfma_f32_32x32x16_f16(Aenc.lo, Bh, acc, 0, 0, 0);
            acc = __builtin_amdgcn_mfma_f32_32x32x16_f16(Aenc.hi, Bl, acc, 0, 0, 0);
            lstm_pointwise(acc, c, h);
        }
#pragma unroll 1
        for (int t = 1; t < OBS_LEN; ++t) {
            // both halves load the same element's obs (same address; L1 serves it)
            const v2f xv = *reinterpret_cast<const v2f*>(op);
            op += ostride;
            v2f xr; xr.x = fmaxf(xv.x, 0.0f); xr.y = fmaxf(xv.y, 0.0f);
            const half8 Bh = build_B_hi(xr, h, half1);
            lstm_step2(Aenc, Bh, kZero, c, h);
        }
    }

    // ---- decoder ----
    const AB Adec = build_A(e, half, Wih_p, Whh_p, bih_p, bhh_p);
    c[0] = splat(0.0f);
    c[1] = splat(0.0f);

    v2f wa[2], wb[2];
    wa[0].x = Wp[4 * half + 0];       wa[0].y = Wp[4 * half + 1];
    wa[1].x = Wp[4 * half + 2];       wa[1].y = Wp[4 * half + 3];
    wb[0].x = Wp[HID + 4 * half + 0]; wb[0].y = Wp[HID + 4 * half + 1];
    wb[1].x = Wp[HID + 4 * half + 2]; wb[1].y = Wp[HID + 4 * half + 3];
    // bias baked into HALF 0's fma accumulator: after the xor-32 sum both
    // halves receive it exactly once (a = p0+bp [half0] + p1 [half1]).
    v2f b0v, b1v;
    b0v.x = half ? 0.0f : bp[0]; b0v.y = 0.0f;
    b1v.x = half ? 0.0f : bp[1]; b1v.y = 0.0f;

    v2f x01 = splat(0.0f);
#pragma unroll 1
    for (int t = 0; t < PRED_LEN; ++t) {
        const half8 Bv = build_B_hi(x01, h, half1);
        lstm_step2(Adec, Bv, kZero, c, h);
        // out = tanh(h @ Wp.T + bp) * SCALE ; h split across lane pairs
        const v2f q0 = vfma(wa[1], h[1], vfma(wa[0], h[0], b0v));
        const v2f q1 = vfma(wb[1], h[1], vfma(wb[0], h[0], b1v));
        float a0 = q0.x + q0.y;
        float a1 = q1.x + q1.y;
        a0 += __shfl_xor(a0, 32);   // both halves now hold the full biased sums
        a1 += __shfl_xor(a1, 32);
        v2f av; av.x = a0; av.y = a1;
        // tanh via rational form, one rcp for the pair:
        // x = (1-ev)/(1+ev)*S = fma(-ev, q, q) with q = inv*S
        const v2f ev = exp2v(av * splat(-2.0f * LOG2E));
        const v2f den = ev + splat(1.0f);
        const float r = __builtin_amdgcn_rcpf(den.x * den.y);
        v2f ds; ds.x = den.y; ds.y = den.x;
        const v2f q = (splat(r) * ds) * splat(SCALE);
        x01 = vfma(-ev, q, q);
        if (!half && ok) {
            *reinterpret_cast<float2*>(out + ((size_t)t * B + eg) * 2) = make_float2(x01.x, x01.y);
        }
    }
}

extern "C" void kernel_launch(void* const* d_in, const int* in_sizes, int n_in,
                              void* d_out, int out_size, void* d_ws, size_t ws_size,
                              hipStream_t stream) {
    const float* obs   = (const float*)d_in[0];
    const float* h0    = (const float*)d_in[1];
    const float* c0    = (const float*)d_in[2];
    const float* Wih_t = (const float*)d_in[3];
    const float* Whh_t = (const float*)d_in[4];
    const float* bih_t = (const float*)d_in[5];
    const float* bhh_t = (const float*)d_in[6];
    const float* Wih_p = (const float*)d_in[7];
    const float* Whh_p = (const float*)d_in[8];
    const float* bih_p = (const float*)d_in[9];
    const float* bhh_p = (const float*)d_in[10];
    const float* Wp    = (const float*)d_in[11];
    const float* bp    = (const float*)d_in[12];
    float* out = (float*)d_out;

    const int B = in_sizes[1] / HID;  // h0 is (B, HID)
    const int grid = (B + ELEMS_PER_BLOCK - 1) / ELEMS_PER_BLOCK;

    hipLaunchKernelGGL(MYLSTM_88201448390683_kernel, dim3(grid), dim3(BLOCK), 0, stream,
                       obs, h0, c0,
                       Wih_t, Whh_t, bih_t, bhh_t,
                       Wih_p, Whh_p, bih_p, bhh_p,
                       Wp, bp, out, B);
}

// Round 7
// 322.155 us; speedup vs baseline: 1.0778x; 1.0231x over previous
//
#include <hip/hip_runtime.h>

#define HID 8
#define OBS_LEN 8
#define PRED_LEN 12
#define SCALE 4.4f
#define BLOCK 256
#define ELEMS_PER_BLOCK 128   // 4 waves * 32 elems per wave

#define LOG2E 1.44269504f
// exp2-arg clamp on the cn (cell) path only (|c| grows ~1/step): cap at 16.
// Gate preacts are structurally bounded -> no clamp needed there.
#define ECLAMP 16.0f

typedef __attribute__((ext_vector_type(8)))  _Float16 half8;
typedef __attribute__((ext_vector_type(2)))  _Float16 half2v;
typedef __attribute__((ext_vector_type(16))) float    f32x16;
typedef __attribute__((ext_vector_type(2)))  float    v2f;

union H8 { half8 v; half2v p[4]; };
struct AB { half8 hi, lo; };
struct H2 { _Float16 hi, lo; };

__device__ __forceinline__ v2f splat(float v) { v2f r; r.x = v; r.y = v; return r; }

__device__ __forceinline__ v2f vfma(v2f a, v2f b, v2f c) {
    return __builtin_elementwise_fma(a, b, c);
}

__device__ __forceinline__ v2f exp2v(v2f a) {
    v2f r;
    r.x = __builtin_amdgcn_exp2f(a.x);
    r.y = __builtin_amdgcn_exp2f(a.y);
    return r;
}

__device__ __forceinline__ half2v pkrtz(float a, float b) {
    return __builtin_bit_cast(half2v, __builtin_amdgcn_cvt_pkrtz(a, b));
}

// scalar split (build_A only — once per phase, off the hot loop), RNE
__device__ __forceinline__ H2 split1(float v) {
    H2 r;
    r.hi = (_Float16)v;
    r.lo = (_Float16)(v - (float)r.hi);
    return r;
}

// Quad-batched reciprocal: 1 v_rcp for FOUR values.
__device__ __forceinline__ void quad_inv(const v2f d[2], v2f inv[2]) {
    const v2f p2 = d[0] * d[1];
    const float r = __builtin_amdgcn_rcpf(p2.x * p2.y);
    const v2f t = splat(r) * p2;
    v2f ts; ts.x = t.y; ts.y = t.x;
    inv[0] = ts * d[1];
    inv[1] = ts * d[0];
}

// A operand, built once per phase.
//   B rows (half p, lane-local):
//     p0: k0-7  = {x0hi, x1hi, h[0..3] (fp16), 1, 0}
//     p1: k8-15 = {x0lo, x1lo, h[4..7] (fp16), 1, 0}
//   A rows: p0: {Wih[m][0..1], Whh[m][0..3], bias[m], 0}
//           p1: {Wih[m][0..1], Whh[m][4..7], 0,       0}
// With Wih-hi present in BOTH halves' x-rows, even a SINGLE A.hi MFMA sees
// Whi*xhi + Whi*xlo = Whi*x — x stays near-exact without the A.lo pass
// (r7 single-MFMA steady state). A.lo (weight residual) is used only at
// encoder step 0, where h0/obs tails make residuals matter.
// exp2 prescale folded into A: i/f/o rows scaled by -log2(e), g rows by
// -2*log2(e), so the MFMA output feeds v_exp_f32 directly.
__device__ __forceinline__ AB build_A(int m, int half_,
    const float* __restrict__ Wih, const float* __restrict__ Whh,
    const float* __restrict__ bih, const float* __restrict__ bhh)
{
    const float k = ((m >> 3) == 2) ? (-2.0f * LOG2E) : (-LOG2E);
    float w[8];
    w[0] = Wih[m * 2 + 0] * k;      // both halves: p0 pairs with xhi, p1 with xlo
    w[1] = Wih[m * 2 + 1] * k;
    if (half_ == 0) {
        w[2] = Whh[m * 8 + 0] * k;
        w[3] = Whh[m * 8 + 1] * k;
        w[4] = Whh[m * 8 + 2] * k;
        w[5] = Whh[m * 8 + 3] * k;
        w[6] = (bih[m] + bhh[m]) * k;
    } else {
        w[2] = Whh[m * 8 + 4] * k;
        w[3] = Whh[m * 8 + 5] * k;
        w[4] = Whh[m * 8 + 6] * k;
        w[5] = Whh[m * 8 + 7] * k;
        w[6] = 0.0f;
    }
    w[7] = 0.0f;
    AB r;
#pragma unroll
    for (int i = 0; i < 8; ++i) {
        const H2 s = split1(w[i]);
        r.hi[i] = s.hi;
        r.lo[i] = s.lo;
    }
    return r;
}

// Steady-state B: exact x split across the half select, RTZ fp16 h.
// (h is quantized per-USE only — the carried state stays f32, so RTZ's
// toward-zero bias does not compound through the recurrence; it enters
// preacts through random-sign Whh like noise. Saves 4 insts vs RNE pack.)
__device__ __forceinline__ half8 build_B(v2f x01, const v2f h[2], bool half1) {
    H8 hi;
    const half2v xh = pkrtz(x01.x, x01.y);
    v2f hc; hc.x = (float)xh.x; hc.y = (float)xh.y;
    const v2f res = x01 - hc;           // Sterbenz-exact residual
    const half2v xl = pkrtz(res.x, res.y);
    hi.p[0] = half1 ? xl : xh;          // 1 cndmask (hoisted cmp)
    hi.p[1] = pkrtz(h[0].x, h[0].y);
    hi.p[2] = pkrtz(h[1].x, h[1].y);
    const half2v one0 = {(_Float16)1.0f, (_Float16)0.0f};
    hi.p[3] = one0;                     // A p1 row6 is 0 -> harmless on half1
    return hi.v;
}

// Step-0-only h-residual operand (h0 ~ N(0,1) is unbounded; fp16 err on
// |h0|~5 reaches ~2e-3 in preact terms — the one step where the residual
// genuinely matters). Residuals are vs the RTZ hi already packed in bh.
__device__ __forceinline__ half8 build_B_lo_h(const v2f h[2], half8 bh) {
    H8 hb; hb.v = bh;
    H8 lo;
    v2f r0; r0.x = h[0].x - (float)hb.p[1].x; r0.y = h[0].y - (float)hb.p[1].y;
    v2f r1; r1.x = h[1].x - (float)hb.p[2].x; r1.y = h[1].y - (float)hb.p[2].y;
    const half2v zz = {(_Float16)0.0f, (_Float16)0.0f};
    lo.p[0] = zz;
    lo.p[1] = pkrtz(r0.x, r0.y);
    lo.p[2] = pkrtz(r1.x, r1.y);
    lo.p[3] = zz;
    return lo.v;
}

// Pointwise LSTM combine, pair-grouped (units {0,1} and {2,3} per lane).
// acc holds exp2-ready args (scale folded into A):
//   ei = 2^acc_i = e^-preact_i, eg = 2^acc_g = e^-2*preact_g
//   sigma = 1/(1+ei), tanh = (1-eg)/(1+eg)
//   cn = (tg*uf + c*ui*vg) / (uf*ui*vg)   ; h = (1-ec)/(uo*(1+ec))
// Strength-reduced: ui*vg = fma(ei,vg,vg); uo*(1+ec) = fma(ec,uo,uo);
// (1-ec)*inv2 = fma(-ec,inv2,inv2). Reciprocals quad-batched: 2 v_rcp/step.
__device__ __forceinline__ void lstm_pointwise(const f32x16& acc, v2f c[2], v2f h[2]) {
    const v2f vone = splat(1.0f);
    v2f num1[2], den1[2], uo[2];
#pragma unroll
    for (int p = 0; p < 2; ++p) {
        v2f ai, af, ag, ao;
        ai.x = acc[2 * p + 0];  ai.y = acc[2 * p + 1];
        af.x = acc[4 + 2 * p];  af.y = acc[5 + 2 * p];
        ag.x = acc[8 + 2 * p];  ag.y = acc[9 + 2 * p];
        ao.x = acc[12 + 2 * p]; ao.y = acc[13 + 2 * p];
        const v2f ei = exp2v(ai);
        const v2f ef = exp2v(af);
        const v2f eg = exp2v(ag);
        const v2f eo = exp2v(ao);
        const v2f uf = ef + vone;
        const v2f vg = eg + vone;
        const v2f tg = vone - eg;
        const v2f uiv = vfma(ei, vg, vg);          // (1+ei)*vg
        num1[p] = vfma(tg, uf, c[p] * uiv);
        den1[p] = uf * uiv;
        uo[p] = eo + vone;
    }
    v2f inv1[2];
    quad_inv(den1, inv1);

    v2f den2[2], ecs[2];
#pragma unroll
    for (int p = 0; p < 2; ++p) {
        const v2f cn = num1[p] * inv1[p];
        c[p] = cn;
        const v2f s0 = cn * splat(-2.0f * LOG2E);
        v2f s; s.x = fminf(s0.x, ECLAMP); s.y = fminf(s0.y, ECLAMP);
        const v2f ec = exp2v(s);
        den2[p] = vfma(ec, uo[p], uo[p]);          // uo*(1+ec)
        ecs[p] = ec;
    }
    v2f inv2[2];
    quad_inv(den2, inv2);
    h[0] = vfma(-ecs[0], inv2[0], inv2[0]);        // (1-ec)*inv2
    h[1] = vfma(-ecs[1], inv2[1], inv2[1]);
}

// Steady-state step: ONE MFMA (A.hi; x exactness carried by the spare-K rows).
__device__ __forceinline__ void lstm_step1(const AB& A, const half8& Bh, const f32x16& Z,
                                           v2f c[2], v2f h[2]) {
    const f32x16 acc = __builtin_amdgcn_mfma_f32_32x32x16_f16(A.hi, Bh, Z, 0, 0, 0);
    lstm_pointwise(acc, c, h);
}

__global__ __launch_bounds__(BLOCK) void MYLSTM_88201448390683_kernel(
    const float* __restrict__ obs,    // (OBS_LEN, B, 2)
    const float* __restrict__ h0,     // (B, HID)
    const float* __restrict__ c0,     // (B, HID)
    const float* __restrict__ Wih_t, const float* __restrict__ Whh_t,
    const float* __restrict__ bih_t, const float* __restrict__ bhh_t,
    const float* __restrict__ Wih_p, const float* __restrict__ Whh_p,
    const float* __restrict__ bih_p, const float* __restrict__ bhh_p,
    const float* __restrict__ Wp,     // (2, HID)
    const float* __restrict__ bp,     // (2,)
    float* __restrict__ out,          // (PRED_LEN, B, 2)
    int B)
{
    const int lane = threadIdx.x & 63;
    const int wid  = threadIdx.x >> 6;
    const int e    = lane & 31;         // element column; also gate row m for A
    const int half = lane >> 5;
    const bool half1 = half != 0;

    int eg = blockIdx.x * ELEMS_PER_BLOCK + wid * 32 + e;
    const bool ok = eg < B;
    if (!ok) eg = 0;

    const f32x16 kZero = {};

    // lane owns units 4*half .. 4*half+3 of element eg (C/D layout:
    // row = (reg&3) + 8*(reg>>2) + 4*half => unit=(reg&3)+4*half, gate=reg>>2)
    v2f h[2], c[2];
    {
        const float4 hv = *reinterpret_cast<const float4*>(h0 + (size_t)eg * HID + half * 4);
        const float4 cv = *reinterpret_cast<const float4*>(c0 + (size_t)eg * HID + half * 4);
        h[0].x = hv.x; h[0].y = hv.y; h[1].x = hv.z; h[1].y = hv.w;
        c[0].x = cv.x; c[0].y = cv.y; c[1].x = cv.z; c[1].y = cv.w;
    }

    // ---- encoder ----
    {
        const AB Aenc = build_A(e, half, Wih_t, Whh_t, bih_t, bhh_t);
        const float* op = obs + (size_t)eg * 2;
        const size_t ostride = (size_t)B * 2;
        // t = 0: h0 unbounded -> keep the residual (3-MFMA) path:
        //   (A.hi + A.lo)*Bh covers weights exactly; A.hi*Bl adds h-residual.
        {
            const v2f xv = *reinterpret_cast<const v2f*>(op);
            op += ostride;
            v2f xr; xr.x = fmaxf(xv.x, 0.0f); xr.y = fmaxf(xv.y, 0.0f);
            const half8 Bh = build_B(xr, h, half1);
            const half8 Bl = build_B_lo_h(h, Bh);
            f32x16 acc = __builtin_amdgcn_mfma_f32_32x32x16_f16(Aenc.hi, Bh, kZero, 0, 0, 0);
            acc = __builtin_amdgcn_mfma_f32_32x32x16_f16(Aenc.lo, Bh, acc, 0, 0, 0);
            acc = __builtin_amdgcn_mfma_f32_32x32x16_f16(Aenc.hi, Bl, acc, 0, 0, 0);
            lstm_pointwise(acc, c, h);
        }
#pragma unroll 1
        for (int t = 1; t < OBS_LEN; ++t) {
            // both halves load the same element's obs (same address; L1 serves it)
            const v2f xv = *reinterpret_cast<const v2f*>(op);
            op += ostride;
            v2f xr; xr.x = fmaxf(xv.x, 0.0f); xr.y = fmaxf(xv.y, 0.0f);
            const half8 Bh = build_B(xr, h, half1);
            lstm_step1(Aenc, Bh, kZero, c, h);
        }
    }

    // ---- decoder ----
    const AB Adec = build_A(e, half, Wih_p, Whh_p, bih_p, bhh_p);
    c[0] = splat(0.0f);
    c[1] = splat(0.0f);

    v2f wa[2], wb[2];
    wa[0].x = Wp[4 * half + 0];       wa[0].y = Wp[4 * half + 1];
    wa[1].x = Wp[4 * half + 2];       wa[1].y = Wp[4 * half + 3];
    wb[0].x = Wp[HID + 4 * half + 0]; wb[0].y = Wp[HID + 4 * half + 1];
    wb[1].x = Wp[HID + 4 * half + 2]; wb[1].y = Wp[HID + 4 * half + 3];
    // bias baked into HALF 0's fma accumulator: after the xor-32 sum both
    // halves receive it exactly once (a = p0+bp [half0] + p1 [half1]).
    v2f b0v, b1v;
    b0v.x = half ? 0.0f : bp[0]; b0v.y = 0.0f;
    b1v.x = half ? 0.0f : bp[1]; b1v.y = 0.0f;

    v2f x01 = splat(0.0f);
#pragma unroll 1
    for (int t = 0; t < PRED_LEN; ++t) {
        const half8 Bv = build_B(x01, h, half1);
        lstm_step1(Adec, Bv, kZero, c, h);
        // out = tanh(h @ Wp.T + bp) * SCALE ; h split across lane pairs
        const v2f q0 = vfma(wa[1], h[1], vfma(wa[0], h[0], b0v));
        const v2f q1 = vfma(wb[1], h[1], vfma(wb[0], h[0], b1v));
        float a0 = q0.x + q0.y;
        float a1 = q1.x + q1.y;
        a0 += __shfl_xor(a0, 32);   // both halves now hold the full biased sums
        a1 += __shfl_xor(a1, 32);
        v2f av; av.x = a0; av.y = a1;
        // tanh via rational form, one rcp for the pair:
        // x = (1-ev)/(1+ev)*S = fma(-ev, q, q) with q = inv*S
        const v2f ev = exp2v(av * splat(-2.0f * LOG2E));
        const v2f den = ev + splat(1.0f);
        const float r = __builtin_amdgcn_rcpf(den.x * den.y);
        v2f ds; ds.x = den.y; ds.y = den.x;
        const v2f q = (splat(r) * ds) * splat(SCALE);
        x01 = vfma(-ev, q, q);
        if (!half && ok) {
            *reinterpret_cast<float2*>(out + ((size_t)t * B + eg) * 2) = make_float2(x01.x, x01.y);
        }
    }
}

extern "C" void kernel_launch(void* const* d_in, const int* in_sizes, int n_in,
                              void* d_out, int out_size, void* d_ws, size_t ws_size,
                              hipStream_t stream) {
    const float* obs   = (const float*)d_in[0];
    const float* h0    = (const float*)d_in[1];
    const float* c0    = (const float*)d_in[2];
    const float* Wih_t = (const float*)d_in[3];
    const float* Whh_t = (const float*)d_in[4];
    const float* bih_t = (const float*)d_in[5];
    const float* bhh_t = (const float*)d_in[6];
    const float* Wih_p = (const float*)d_in[7];
    const float* Whh_p = (const float*)d_in[8];
    const float* bih_p = (const float*)d_in[9];
    const float* bhh_p = (const float*)d_in[10];
    const float* Wp    = (const float*)d_in[11];
    const float* bp    = (const float*)d_in[12];
    float* out = (float*)d_out;

    const int B = in_sizes[1] / HID;  // h0 is (B, HID)
    const int grid = (B + ELEMS_PER_BLOCK - 1) / ELEMS_PER_BLOCK;

    hipLaunchKernelGGL(MYLSTM_88201448390683_kernel, dim3(grid), dim3(BLOCK), 0, stream,
                       obs, h0, c0,
                       Wih_t, Whh_t, bih_t, bhh_t,
                       Wih_p, Whh_p, bih_p, bhh_p,
                       Wp, bp, out, B);
}